// Round 7
// baseline (479.636 us; speedup 1.0000x reference)
//
#include <hip/hip_runtime.h>

#define N_NODES 50000
#define E_EDGES 262144

typedef __attribute__((ext_vector_type(8))) short bf16x8;
typedef __attribute__((ext_vector_type(4))) float f32x4;

union V16 { uint4 u; bf16x8 h; };

__device__ __forceinline__ unsigned rne_pack(float a, float b) {
  unsigned ua = __float_as_uint(a); ua += 0x7fffu + ((ua >> 16) & 1u);
  unsigned ub = __float_as_uint(b); ub += 0x7fffu + ((ub >> 16) & 1u);
  return (ua >> 16) | (ub & 0xffff0000u);
}
__device__ __forceinline__ float bflo(unsigned u) { return __uint_as_float(u << 16); }
__device__ __forceinline__ float bfhi(unsigned u) { return __uint_as_float(u & 0xffff0000u); }
// (bits(a)>>16) | (bits(b)&0xffff0000) in one v_perm_b32
__device__ __forceinline__ unsigned perm_pack(float a, float b) {
  return __builtin_amdgcn_perm(__float_as_uint(b), __float_as_uint(a), 0x07060302u);
}
__device__ __forceinline__ void async_gather16(const void* gptr, void* lptr) {
  __builtin_amdgcn_global_load_lds(
      (const __attribute__((address_space(1))) void*)gptr,
      (__attribute__((address_space(3))) void*)lptr, 16, 0, 0);
}

// ---- prep: node_repr fp32 -> bf16 (RNE) ----
__global__ void cvt_node_kernel(const float* __restrict__ x, unsigned short* __restrict__ y) {
  int i = (blockIdx.x * 256 + threadIdx.x) * 8;
  float4 f0 = *(const float4*)(x + i);
  float4 f1 = *(const float4*)(x + i + 4);
  uint4 o;
  o.x = rne_pack(f0.x, f0.y);
  o.y = rne_pack(f0.z, f0.w);
  o.z = rne_pack(f1.x, f1.y);
  o.w = rne_pack(f1.z, f1.w);
  *(uint4*)(y + i) = o;
}

// ---- prep: W1 (1024x512 row-major in->out) -> W1pp2 bf16, 16-B units laid out
// [step(8)][sq=s*4+quad(16)][col(512)], unit = W1[k0..k0+8)[col], k0=s*256+step*32+quad*8
__global__ void prep_w1pp2_kernel(const float* __restrict__ w1, unsigned short* __restrict__ w1pp2) {
  int t = blockIdx.x * 256 + threadIdx.x;  // 65536 units
  int step = t >> 13;
  int rem = t & 8191;
  int sq = rem >> 9;
  int col = rem & 511;
  int s = sq >> 2, qd = sq & 3;
  int k0 = s * 256 + step * 32 + qd * 8;
  float f[8];
#pragma unroll
  for (int i = 0; i < 8; ++i) f[i] = w1[(size_t)(k0 + i) * 512 + col];
  uint4 o;
  o.x = rne_pack(f[0], f[1]);
  o.y = rne_pack(f[2], f[3]);
  o.z = rne_pack(f[4], f[5]);
  o.w = rne_pack(f[6], f[7]);
  *(uint4*)(w1pp2 + (size_t)t * 8) = o;
}

// ---- prep: out[e][c] = b2[c] ----
__global__ void init_out_kernel(float* __restrict__ out, const float* __restrict__ b2) {
  int i = blockIdx.x * 256 + threadIdx.x;
  float2 v; v.x = b2[0]; v.y = b2[1];
  *(float2*)(out + (size_t)i * 2) = v;
}

// ---- main fused kernel: 1 barrier/step; A via LDS dbuf, B register-pipelined 1 step ahead ----
__global__ __launch_bounds__(256, 2) void edge_mlp_kernel(
    const unsigned short* __restrict__ nodeb,  // [50000][256] bf16
    const unsigned short* __restrict__ w1pp2,  // repacked W1 (see prep)
    const int* __restrict__ src,
    const int* __restrict__ dst,
    const float* __restrict__ b1,
    const float* __restrict__ w2,   // [512][2] fp32
    float* __restrict__ out) {      // [E][2] fp32, pre-init with b2
  // A buffers: buf p at [p*16K, p*16K+16K): hi 8K | hj 8K
  __shared__ char smem[32768];

  const int tid = threadIdx.x;
  const int wid = tid >> 6;
  const int lane = tid & 63;
  const int quad = lane >> 4;
  const int l16 = lane & 15;
  const int bx = blockIdx.x;
  const int m_idx = ((bx >> 5) << 3) + (bx & 7);  // sibling n-blocks -> same XCD
  const int n_idx = (bx >> 3) & 3;
  const int wave_m = wid >> 1;
  const int wave_n = wid & 1;
  const int row0 = m_idx * 128;
  const int wrow0 = row0 + wave_m * 64;
  const int n0 = n_idx * 128 + wave_n * 64;

  const char* nodeB = (const char*)nodeb;
  const char* w1B = (const char*)w1pp2;

  // ---- A stager state: unit u=c*256+tid -> e=u>>2, LDS slot holds global quad (tid&3)^((tid>>3)&3)
  const int eh = tid >> 2;
  const unsigned qsw = (unsigned)(((tid & 3) ^ ((tid >> 3) & 3)) << 4);
  const unsigned oi0 = ((unsigned)src[row0 + eh] << 9) + qsw;
  const unsigned oi1 = ((unsigned)src[row0 + 64 + eh] << 9) + qsw;
  const unsigned oj0 = ((unsigned)dst[row0 + eh] << 9) + qsw;
  const unsigned oj1 = ((unsigned)dst[row0 + 64 + eh] << 9) + qsw;
  const unsigned sdst = (unsigned)(wid * 1024);  // wave-uniform LDS dest offset

  // ---- B register-load offsets: (s*4+quad)*8192 + (n0 + l16)*16  (+ step*131072)
  unsigned bOff[4];
#pragma unroll
  for (int s = 0; s < 4; ++s)
    bOff[s] = (unsigned)((s * 4 + quad) * 8192 + (n0 + l16) * 16);

  // ---- A reader base ----
  const unsigned aR = (unsigned)((wave_m * 64 + l16) * 64 + ((quad ^ ((l16 >> 1) & 3)) << 4));

  f32x4 acc[4][4];
#pragma unroll
  for (int mt = 0; mt < 4; ++mt)
#pragma unroll
    for (int nt = 0; nt < 4; ++nt)
      acc[mt][nt] = (f32x4){0.f, 0.f, 0.f, 0.f};

  // ---- prologue: stage A(0) into buf0; load B(0) into registers ----
  async_gather16(nodeB + oi0, smem + sdst);
  async_gather16(nodeB + oi1, smem + 4096 + sdst);
  async_gather16(nodeB + oj0, smem + 8192 + sdst);
  async_gather16(nodeB + oj1, smem + 12288 + sdst);
  V16 bfc[4][4];
#pragma unroll
  for (int s = 0; s < 4; ++s)
#pragma unroll
    for (int nt = 0; nt < 4; ++nt)
      bfc[s][nt].u = *(const uint4*)(w1B + bOff[s] + nt * 256);
  __syncthreads();

  int p = 0;
#pragma unroll 2
  for (int step = 0; step < 8; ++step) {
    const char* Acur = smem + (p << 14);
    // 1) A fragments from LDS first (also pins LDS order: gathers below can't hoist above)
    V16 hi[4], hj[4];
#pragma unroll
    for (int mt = 0; mt < 4; ++mt) {
      hi[mt].u = *(const uint4*)(Acur + aR + mt * 1024);
      hj[mt].u = *(const uint4*)(Acur + 8192 + aR + mt * 1024);
    }
    // 2) A(step+1) gathers -> other buffer; full compute phase in flight before barrier drain
    if (step < 7) {
      const unsigned aoN = (unsigned)(step + 1) * 64u;
      char* Aalt = smem + ((p ^ 1) << 14);
      async_gather16(nodeB + (oi0 + aoN), Aalt + sdst);
      async_gather16(nodeB + (oi1 + aoN), Aalt + 4096 + sdst);
      async_gather16(nodeB + (oj0 + aoN), Aalt + 8192 + sdst);
      async_gather16(nodeB + (oj1 + aoN), Aalt + 12288 + sdst);
    }
    // 3) compute s=0 (hi), s=1 (hj) — operands all in registers/LDS, no vm wait
#pragma unroll
    for (int sl = 0; sl < 2; ++sl) {
#pragma unroll
      for (int mt = 0; mt < 4; ++mt) {
        bf16x8 af = (sl == 0) ? hi[mt].h : hj[mt].h;
#pragma unroll
        for (int nt = 0; nt < 4; ++nt)
          acc[mt][nt] = __builtin_amdgcn_mfma_f32_16x16x32_bf16(af, bfc[sl][nt].h, acc[mt][nt], 0, 0, 0);
      }
    }
    // 4) B(step+1) register loads (L2-resident); consumed only after next barrier
    V16 bfn[4][4];
    if (step < 7) {
      const unsigned wstepN = (unsigned)(step + 1) * 131072u;
#pragma unroll
      for (int s = 0; s < 4; ++s)
#pragma unroll
        for (int nt = 0; nt < 4; ++nt)
          bfn[s][nt].u = *(const uint4*)(w1B + (wstepN + bOff[s]) + nt * 256);
    }
    // 5) build a2/a3 and compute s=2,3
#pragma unroll
    for (int mt = 0; mt < 4; ++mt) {
      const unsigned hw[4] = {hi[mt].u.x, hi[mt].u.y, hi[mt].u.z, hi[mt].u.w};
      const unsigned jw[4] = {hj[mt].u.x, hj[mt].u.y, hj[mt].u.z, hj[mt].u.w};
      unsigned d[4], pr[4];
#pragma unroll
      for (int w = 0; w < 4; ++w) {
        float i0 = bflo(hw[w]), i1 = bfhi(hw[w]);
        float j0 = bflo(jw[w]), j1 = bfhi(jw[w]);
        d[w] = perm_pack(i0 - j0, i1 - j1) & 0x7fff7fffu;
        pr[w] = perm_pack(i0 * j0, i1 * j1);
      }
      V16 a2, a3;
      a2.u = make_uint4(d[0], d[1], d[2], d[3]);
      a3.u = make_uint4(pr[0], pr[1], pr[2], pr[3]);
#pragma unroll
      for (int nt = 0; nt < 4; ++nt)
        acc[mt][nt] = __builtin_amdgcn_mfma_f32_16x16x32_bf16(a2.h, bfc[2][nt].h, acc[mt][nt], 0, 0, 0);
#pragma unroll
      for (int nt = 0; nt < 4; ++nt)
        acc[mt][nt] = __builtin_amdgcn_mfma_f32_16x16x32_bf16(a3.h, bfc[3][nt].h, acc[mt][nt], 0, 0, 0);
    }
    __syncthreads();  // drains A(t+1) gathers + B(t+1) loads — both have long flight
    if (step < 7) {
#pragma unroll
      for (int s = 0; s < 4; ++s)
#pragma unroll
        for (int nt = 0; nt < 4; ++nt)
          bfc[s][nt] = bfn[s][nt];  // killed by copy-prop under unroll-2
    }
    p ^= 1;
  }

  // ---- epilogue: bias + ReLU + W2, 16-lane shuffle reduce, atomic out ----
#pragma unroll
  for (int mt = 0; mt < 4; ++mt) {
    float pc0[4] = {0.f, 0.f, 0.f, 0.f};
    float pc1[4] = {0.f, 0.f, 0.f, 0.f};
#pragma unroll
    for (int nt = 0; nt < 4; ++nt) {
      int gc = n0 + nt * 16 + l16;
      float b1v = b1[gc];
      float w20 = w2[gc * 2 + 0];
      float w21 = w2[gc * 2 + 1];
#pragma unroll
      for (int r = 0; r < 4; ++r) {
        float v = fmaxf(acc[mt][nt][r] + b1v, 0.f);
        pc0[r] = fmaf(v, w20, pc0[r]);
        pc1[r] = fmaf(v, w21, pc1[r]);
      }
    }
#pragma unroll
    for (int r = 0; r < 4; ++r) {
      float s0 = pc0[r], s1 = pc1[r];
#pragma unroll
      for (int off = 1; off < 16; off <<= 1) {
        s0 += __shfl_xor(s0, off);
        s1 += __shfl_xor(s1, off);
      }
      int e = wrow0 + mt * 16 + quad * 4 + r;  // C/D: row = quad*4 + r
      if (l16 == 0) unsafeAtomicAdd(&out[(size_t)e * 2 + 0], s0);
      if (l16 == 1) unsafeAtomicAdd(&out[(size_t)e * 2 + 1], s1);
    }
  }
}

extern "C" void kernel_launch(void* const* d_in, const int* in_sizes, int n_in,
                              void* d_out, int out_size, void* d_ws, size_t ws_size,
                              hipStream_t stream) {
  const float* node = (const float*)d_in[0];
  const int* src = (const int*)d_in[1];
  const int* dst = (const int*)d_in[2];
  const float* W1 = (const float*)d_in[3];
  const float* b1 = (const float*)d_in[4];
  const float* W2 = (const float*)d_in[5];
  const float* b2 = (const float*)d_in[6];
  float* out = (float*)d_out;

  unsigned short* nodeb = (unsigned short*)d_ws;                      // 25,600,000 B
  unsigned short* w1pp2 = (unsigned short*)((char*)d_ws + 25600000);  // 1,048,576 B

  cvt_node_kernel<<<6250, 256, 0, stream>>>(node, nodeb);
  prep_w1pp2_kernel<<<256, 256, 0, stream>>>(W1, w1pp2);
  init_out_kernel<<<1024, 256, 0, stream>>>(out, b2);
  edge_mlp_kernel<<<8192, 256, 0, stream>>>(nodeb, w1pp2, src, dst, b1, W2, out);
}